// Round 7
// baseline (176.419 us; speedup 1.0000x reference)
//
#include <hip/hip_runtime.h>

// Until operator: r[t] = max( min(1,psi[t]), min(phi[t], r[t+1]) ), r[T] = -inf.
// f(x)=max(a,min(b,x)) closed under composition (f earlier in time):
//   (f o g): A = max(a_f, min(b_f, a_g)), B = min(b_f, b_g)
// float4 = 2 timesteps x 2 channels = one "pair entry". Row = 4096 entries.
//
// R10: FULLY LANE-LOCAL structure. Evidence: R4-R9b fit t = ~50us + bytes/
// 8.7TBps -- a structure-invariant floor no counter explains; occupancy
// (R7), intra-block pipelining + non-draining barriers (R8) and nt stores
// (R9b) are all null. The one element never removed is the per-block LDS
// skeleton (transpose round-trip + fences + carry round-trip). This kernel
// deletes it: each LANE owns 4 CONSECUTIVE entries end-to-end (load -> G ->
// compose -> scan -> carry -> emit, all in registers). Loads/stores become
// 64B-strided dwordx4 (lane pairs share 128B lines; each k-group fully
// covers its 4KB span; ~2x VMEM requests, irrelevant at 25% BW). Remaining
// shared state: the 64-lane shuffle suffix-scan (unchanged) + one 256B ssum
// exchange + ONE __syncthreads. LDS 66KB -> 256B. Block = 16 waves = one
// row; launch_bounds(1024,8) -> 2 blocks/CU = 2048 thr/CU = 100% static
// occupancy. Live regs ~50 (P/V held to emit; G folded on the fly, never
// stored). WRITE_SIZE=65536KB is the spill canary (R5 lesson).
// Falsifiable: if this nulls at ~66us, the floor is the memory system's
// bursty-working-set behavior in this environment -> declare roofline.

#define T_LEN 8192
#define NW    16            // waves per block; wave = 256 consecutive entries
#define BLOCK (NW * 64)     // 1024 threads = one row (4096 entries)

__global__ __launch_bounds__(BLOCK, 8) void until_kernel(
    const float* __restrict__ phi, const float* __restrict__ psi,
    float* __restrict__ out)
{
    const int  row  = blockIdx.x;
    const int  tid  = threadIdx.x;
    const int  w    = tid >> 6;
    const int  lane = tid & 63;
    const float NEG = -__builtin_huge_valf();
    const float POS =  __builtin_huge_valf();

    // lane owns 4 CONSECUTIVE float4 entries starting here
    const size_t base = (size_t)row * (T_LEN / 2) + (size_t)w * 256
                      + (size_t)lane * 4;
    const float4* __restrict__ phi4 = (const float4*)phi + base;
    const float4* __restrict__ psi4 = (const float4*)psi + base;
    float4* __restrict__ out4 = (float4*)out + base;

    __shared__ float4 ssum[NW];   // the ONLY LDS: per-wave summaries

    // ---- burst: 8 loads (4 phi + 4 psi), one shared voffset + imm offsets ----
    float4 P[4], V[4];
#pragma unroll
    for (int k = 0; k < 4; ++k) {
        P[k] = phi4[k];
        V[k] = psi4[k];
    }
#pragma unroll
    for (int k = 0; k < 4; ++k) {
        V[k].x = fminf(1.f, V[k].x);
        V[k].y = fminf(1.f, V[k].y);
        V[k].z = fminf(1.f, V[k].z);
        V[k].w = fminf(1.f, V[k].w);
    }

    // ---- build + fold entry functions right-to-left, all in registers ----
    // entry k: A = max(v0, min(p0, v1)), B = min(p0, p1)
    float hax = fmaxf(V[3].x, fminf(P[3].x, V[3].z));
    float hay = fmaxf(V[3].y, fminf(P[3].y, V[3].w));
    float hbx = fminf(P[3].x, P[3].z);
    float hby = fminf(P[3].y, P[3].w);
#pragma unroll
    for (int k = 2; k >= 0; --k) {
        float ax = fmaxf(V[k].x, fminf(P[k].x, V[k].z));
        float ay = fmaxf(V[k].y, fminf(P[k].y, V[k].w));
        float bx = fminf(P[k].x, P[k].z);
        float by = fminf(P[k].y, P[k].w);
        hax = fmaxf(ax, fminf(bx, hax));
        hay = fmaxf(ay, fminf(by, hay));
        hbx = fminf(bx, hbx);
        hby = fminf(by, hby);
    }

    // ---- 64-lane inclusive SUFFIX scan (toward lane 63) ----
#pragma unroll
    for (int off = 1; off < 64; off <<= 1) {
        float gax = __shfl_down(hax, off), gay = __shfl_down(hay, off);
        float gbx = __shfl_down(hbx, off), gby = __shfl_down(hby, off);
        bool  val = (lane + off) < 64;
        gax = val ? gax : NEG;  gay = val ? gay : NEG;
        gbx = val ? gbx : POS;  gby = val ? gby : POS;
        hax = fmaxf(hax, fminf(hbx, gax));
        hay = fmaxf(hay, fminf(hby, gay));
        hbx = fminf(hbx, gbx);
        hby = fminf(hby, gby);
    }
    const float Sax = hax, Say = hay, Sbx = hbx, Sby = hby;

    // ---- wave summary -> ssum; ONE barrier; combine later waves ----
    if (lane == 0) ssum[w] = make_float4(Sax, Say, Sbx, Sby);
    __syncthreads();
    float rcx = NEG, rcy = NEG;   // carry entering this wave's right edge
    for (int j = NW - 1; j > w; --j) {
        float4 s = ssum[j];       // uniform address: broadcast, conflict-free
        rcx = fmaxf(s.x, fminf(s.z, rcx));
        rcy = fmaxf(s.y, fminf(s.w, rcy));
    }

    // ---- lane carry: y = value at lane's LEFT edge = S[lane](rc) ----
    float yx = fmaxf(Sax, fminf(Sbx, rcx));
    float yy = fmaxf(Say, fminf(Sby, rcy));
    // carry entering lane's rightmost entry = y_{lane+1} (lane 63: rc)
    float cx = __shfl_down(yx, 1), cy = __shfl_down(yy, 1);
    if (lane == 63) { cx = rcx; cy = rcy; }

    // ---- lane-local emit, right-to-left; carry chains through registers ----
#pragma unroll
    for (int k = 3; k >= 0; --k) {
        float r1x = fmaxf(V[k].z, fminf(P[k].z, cx));
        float r1y = fmaxf(V[k].w, fminf(P[k].w, cy));
        float r0x = fmaxf(V[k].x, fminf(P[k].x, r1x));
        float r0y = fmaxf(V[k].y, fminf(P[k].y, r1y));
        out4[k] = make_float4(r0x, r0y, r1x, r1y);
        cx = r0x;   // carry into the previous (earlier) entry
        cy = r0y;
    }
}

extern "C" void kernel_launch(void* const* d_in, const int* in_sizes, int n_in,
                              void* d_out, int out_size, void* d_ws, size_t ws_size,
                              hipStream_t stream) {
    const float* phi = (const float*)d_in[0];
    const float* psi = (const float*)d_in[1];
    float* out = (float*)d_out;
    const int Bn = in_sizes[0] / (T_LEN * 2);  // = 1024
    until_kernel<<<Bn, BLOCK, 0, stream>>>(phi, psi, out);
}

// Round 8
// 174.584 us; speedup vs baseline: 1.0105x; 1.0105x over previous
//
#include <hip/hip_runtime.h>

// Until operator: r[t] = max( min(1,psi[t]), min(phi[t], r[t+1]) ), r[T] = -inf.
// f(x)=max(a,min(b,x)) closed under composition (f earlier in time):
//   (f o g): A = max(a_f, min(b_f, a_g)), B = min(b_f, b_g)
// float4 = 2 timesteps x 2 channels = one "pair entry". Row = 4096 entries.
// block = one row (8 waves); wave = contiguous 512-entry segment.
//
// R11 = REVERT to R6, the session's best (66us/dispatch, 174.6us harness).
// Final evidence chain:
//   R6  traffic cut (no emit reload; FETCH 128->65.6MB)      -8us  WIN
//   R7  occupancy x2 (31->65%) at same structure              null
//   R8  2-row pipeline + non-vmcnt-draining barriers          null
//   R9b non-temporal stores (nt emitted; FETCH unchanged)     null
//   R10 delete entire LDS skeleton (66KB->512B, 0 fences)     null (+6us)
// => t = ~50us structure-invariant floor + hbm_bytes at ~peak marginal BW.
// Remaining FETCH (= half the inputs) is pinned by HARNESS eviction: the
// bench's reset/poison writes + 64MB output stream cycle ~128MB of
// non-input lines through the 256MB L3 each iteration, evicting half the
// 128MB inputs regardless of kernel-side store policy (R9b proves store
// policy is irrelevant). All kernel-controllable counters are at their
// floor; all structural levers tested and falsified. This is the keeper.
// (R5 lesson kept: never cap VGPR below peak live set via launch_bounds.)

#define T_LEN 8192
#define NSEG  8            // waves per block = segments per row
#define BLOCK (NSEG * 64)  // 512

__device__ __forceinline__ float rfl(float x) {
    return __int_as_float(__builtin_amdgcn_readfirstlane(__float_as_int(x)));
}

// Wave-level ordering fence for wave-private LDS reuse: prevents the compiler
// from moving LDS accesses across it; HW executes a wave's DS ops in order.
__device__ __forceinline__ void wave_lds_fence() {
    __asm__ volatile("" ::: "memory");
    __builtin_amdgcn_wave_barrier();
    __asm__ volatile("" ::: "memory");
}

__global__ __launch_bounds__(BLOCK, 4) void until_kernel(
    const float* __restrict__ phi, const float* __restrict__ psi,
    float* __restrict__ out)
{
    const int  row  = blockIdx.x;
    const int  tid  = threadIdx.x;
    const int  w    = tid >> 6;
    const int  lane = tid & 63;
    const float NEG = -__builtin_huge_valf();
    const float POS =  __builtin_huge_valf();

    const size_t segf4 = (size_t)row * (T_LEN / 2) + (size_t)w * 512;
    const float4* __restrict__ phi4 = (const float4*)phi + segf4;
    const float4* __restrict__ psi4 = (const float4*)psi + segf4;
    float4* __restrict__ out4 = (float4*)out + segf4;

    // Per-wave private 2048-float region:
    //   G phase:  round r in [r*1024, r*1024+1024): 4 SoA comps x 256 entries
    //   carry phase (reuses round-0 area): CX[e] at wl[e], CY[e] at wl[512+e]
    __shared__ alignas(16) float lds[NSEG * 2048];
    __shared__ float4 ssum[NSEG];
    float* wl = lds + w * 2048;

    // ---- burst: issue all 16 global loads back-to-back ----
    // P = phi raw; V = min(1, psi) folded at load (psi raw never needed again)
    float4 P[8], V[8];
#pragma unroll
    for (int k = 0; k < 8; ++k) {
        P[k] = phi4[k * 64 + lane];
        V[k] = psi4[k * 64 + lane];
    }
#pragma unroll
    for (int k = 0; k < 8; ++k) {
        V[k].x = fminf(1.f, V[k].x);
        V[k].y = fminf(1.f, V[k].y);
        V[k].z = fminf(1.f, V[k].z);
        V[k].w = fminf(1.f, V[k].w);
    }

    // ---- build pair functions G, SoA write (dense, conflict-free) ----
#pragma unroll
    for (int k = 0; k < 8; ++k) {
        const int r  = k >> 2;
        const int kl = k & 3;
        float* base = wl + r * 1024 + kl * 64 + lane;
        base[0]   = fmaxf(V[k].x, fminf(P[k].x, V[k].z));  // GAx
        base[256] = fmaxf(V[k].y, fminf(P[k].y, V[k].w));  // GAy
        base[512] = fminf(P[k].x, P[k].z);                 // GBx
        base[768] = fminf(P[k].y, P[k].w);                 // GBy
    }
    wave_lds_fence();   // wave-private transpose: no block barrier needed

    // ---- transposed read (b128, dense) + compose + suffix scan per round ----
    float4 GAx[2], GAy[2], GBx[2], GBy[2];
    float  Sax[2], Say[2], Sbx[2], Sby[2];
#pragma unroll
    for (int r = 0; r < 2; ++r) {
        const float* rb = wl + r * 1024;
        GAx[r] = *(const float4*)(rb + 0 * 256 + lane * 4);
        GAy[r] = *(const float4*)(rb + 1 * 256 + lane * 4);
        GBx[r] = *(const float4*)(rb + 2 * 256 + lane * 4);
        GBy[r] = *(const float4*)(rb + 3 * 256 + lane * 4);

        // local compose right-to-left: H = G_j0 o G_j1 o G_j2 o G_j3
        float hax = GAx[r].w, hay = GAy[r].w, hbx = GBx[r].w, hby = GBy[r].w;
        hax = fmaxf(GAx[r].z, fminf(GBx[r].z, hax));
        hay = fmaxf(GAy[r].z, fminf(GBy[r].z, hay));
        hbx = fminf(GBx[r].z, hbx);
        hby = fminf(GBy[r].z, hby);
        hax = fmaxf(GAx[r].y, fminf(GBx[r].y, hax));
        hay = fmaxf(GAy[r].y, fminf(GBy[r].y, hay));
        hbx = fminf(GBx[r].y, hbx);
        hby = fminf(GBy[r].y, hby);
        hax = fmaxf(GAx[r].x, fminf(GBx[r].x, hax));
        hay = fmaxf(GAy[r].x, fminf(GBy[r].x, hay));
        hbx = fminf(GBx[r].x, hbx);
        hby = fminf(GBy[r].x, hby);

        // 64-lane inclusive SUFFIX scan (toward lane 63)
#pragma unroll
        for (int off = 1; off < 64; off <<= 1) {
            float gax = __shfl_down(hax, off), gay = __shfl_down(hay, off);
            float gbx = __shfl_down(hbx, off), gby = __shfl_down(hby, off);
            bool  val = (lane + off) < 64;
            gax = val ? gax : NEG;  gay = val ? gay : NEG;
            gbx = val ? gbx : POS;  gby = val ? gby : POS;
            hax = fmaxf(hax, fminf(hbx, gax));
            hay = fmaxf(hay, fminf(hby, gay));
            hbx = fminf(hbx, gbx);
            hby = fminf(hby, gby);
        }
        Sax[r] = hax; Say[r] = hay; Sbx[r] = hbx; Sby[r] = hby;
    }

    // ---- segment summary W = R0 o R1 -> ssum (the ONE real barrier) ----
    float R0ax = rfl(Sax[0]), R0ay = rfl(Say[0]);
    float R0bx = rfl(Sbx[0]), R0by = rfl(Sby[0]);
    float R1ax = rfl(Sax[1]), R1ay = rfl(Say[1]);
    float R1bx = rfl(Sbx[1]), R1by = rfl(Sby[1]);
    if (lane == 0) {
        float wax = fmaxf(R0ax, fminf(R0bx, R1ax));
        float way = fmaxf(R0ay, fminf(R0by, R1ay));
        float wbx = fminf(R0bx, R1bx);
        float wby = fminf(R0by, R1by);
        ssum[w] = make_float4(wax, way, wbx, wby);
    }
    __syncthreads();
    float rcx = NEG, rcy = NEG;   // carry entering this segment's right edge
    for (int j = NSEG - 1; j > w; --j) {
        float4 s = ssum[j];
        rcx = fmaxf(s.x, fminf(s.z, rcx));
        rcy = fmaxf(s.y, fminf(s.w, rcy));
    }

    // carries entering each round (round 0 sees round 1 applied first)
    float rinx[2], riny[2];
    rinx[1] = rcx;
    riny[1] = rcy;
    rinx[0] = fmaxf(R1ax, fminf(R1bx, rcx));
    riny[0] = fmaxf(R1ay, fminf(R1by, rcy));

    // ---- per-entry carries -> wave-private LDS (b128, dense) ----
#pragma unroll
    for (int r = 0; r < 2; ++r) {
        // y = value at lane's LEFT edge = S_r[lane](r_in)
        float yx = fmaxf(Sax[r], fminf(Sbx[r], rinx[r]));
        float yy = fmaxf(Say[r], fminf(Sby[r], riny[r]));
        // carry entering lane's rightmost entry = y_{lane+1} (lane63: r_in)
        float cx = __shfl_down(yx, 1), cy = __shfl_down(yy, 1);
        if (lane == 63) { cx = rinx[r]; cy = riny[r]; }
        float4 CX, CY;
        CX.w = cx;
        CY.w = cy;
        CX.z = fmaxf(GAx[r].w, fminf(GBx[r].w, CX.w));
        CY.z = fmaxf(GAy[r].w, fminf(GBy[r].w, CY.w));
        CX.y = fmaxf(GAx[r].z, fminf(GBx[r].z, CX.z));
        CY.y = fmaxf(GAy[r].z, fminf(GBy[r].z, CY.z));
        CX.x = fmaxf(GAx[r].y, fminf(GBx[r].y, CX.y));
        CY.x = fmaxf(GAy[r].y, fminf(GBy[r].y, CY.y));
        *(float4*)(wl +       r * 256 + lane * 4) = CX;  // CX[e] at wl[e]
        *(float4*)(wl + 512 + r * 256 + lane * 4) = CY;  // CY[e] at wl[512+e]
    }
    wave_lds_fence();   // wave-private carry handoff: no block barrier

    // ---- emit outputs from REGISTERS (no global reload) + carry from LDS ----
#pragma unroll
    for (int k = 0; k < 8; ++k) {
        const int e = k * 64 + lane;
        float cx = wl[e];          // r at this entry's right edge
        float cy = wl[512 + e];
        float r1x = fmaxf(V[k].z, fminf(P[k].z, cx));
        float r1y = fmaxf(V[k].w, fminf(P[k].w, cy));
        float r0x = fmaxf(V[k].x, fminf(P[k].x, r1x));
        float r0y = fmaxf(V[k].y, fminf(P[k].y, r1y));
        out4[e] = make_float4(r0x, r0y, r1x, r1y);
    }
}

extern "C" void kernel_launch(void* const* d_in, const int* in_sizes, int n_in,
                              void* d_out, int out_size, void* d_ws, size_t ws_size,
                              hipStream_t stream) {
    const float* phi = (const float*)d_in[0];
    const float* psi = (const float*)d_in[1];
    float* out = (float*)d_out;
    const int Bn = in_sizes[0] / (T_LEN * 2);  // = 1024
    until_kernel<<<Bn, BLOCK, 0, stream>>>(phi, psi, out);
}